// Round 3
// baseline (59.832 us; speedup 1.0000x reference)
//
#include <hip/hip_runtime.h>
#include <stdint.h>

#define B_ 4
#define C_ 1
#define D_ 128
#define HW_ 65536          // 256*256
#define K_ 4
#define NBC (B_*C_)
#define SCALE_ 100000.0f
#define EPS_ 1e-15f

__global__ __launch_bounds__(64) void init_mm_kernel(unsigned int* mm) {
    int t = threadIdx.x;
    if (t < NBC) {
        mm[2*t]   = 0x7F800000u;  // +inf  (min slot)
        mm[2*t+1] = 0u;           // 0.0f  (max slot; all values >= 0)
    }
}

// One thread per (b,c,h,w) column: scalar loads (64-lane contiguous 256B per
// wave-load), full 128-depth scan, branchless top-4 insertion. No cross-thread
// merge needed. Strict > insertion with ascending d == lax.top_k tie-break.
__global__ __launch_bounds__(256, 4) void topk_kernel(const float* __restrict__ x,
                                                      float* __restrict__ out,
                                                      unsigned int* __restrict__ mm) {
    const int tid = blockIdx.x * 256 + threadIdx.x;   // column id 0..262143
    const int bc  = tid >> 16;                        // / HW_
    const int hw  = tid & (HW_ - 1);
    const float* __restrict__ src = x + (size_t)bc * (D_ * HW_) + hw;

    float lv[K_];
    int   li[K_];
    #pragma unroll
    for (int k = 0; k < K_; ++k) { lv[k] = -1.0f; li[k] = 0; }

    float mn = __int_as_float(0x7F800000);            // +inf

    #pragma unroll 8
    for (int d = 0; d < D_; ++d) {
        const float v = fmaxf(src[(size_t)d * HW_], 0.0f);
        mn = fminf(mn, v);
        // insert at bottom (strict >: equal value keeps earlier depth)
        const bool ins = v > lv[3];
        lv[3] = ins ? v : lv[3];
        li[3] = ins ? d : li[3];
        // bubble up (strict >: stable for ties)
        #pragma unroll
        for (int k = 3; k > 0; --k) {
            const bool sw = lv[k] > lv[k-1];
            const float tv = sw ? lv[k-1] : lv[k];
            const int   ti = sw ? li[k-1] : li[k];
            lv[k-1] = sw ? lv[k] : lv[k-1];
            li[k-1] = sw ? li[k] : li[k-1];
            lv[k] = tv;  li[k] = ti;
        }
    }

    // write raw top-4 values (normalized later) + dep channel; coalesced
    // across threads (consecutive hw -> contiguous 1KB per wave-store)
    const size_t obase = (size_t)(bc * 2 * K_) * HW_ + hw;
    #pragma unroll
    for (int k = 0; k < K_; ++k) {
        out[obase + (size_t)k * HW_]        = lv[k];
        out[obase + (size_t)(K_ + k) * HW_] = (float)(D_ - 1 - li[k]) * (1.0f / 127.0f);
    }

    // block reduce min/max -> one atomic pair per block (block shares bc)
    float mx = lv[0];
    #pragma unroll
    for (int off = 32; off > 0; off >>= 1) {
        mn = fminf(mn, __shfl_xor(mn, off));
        mx = fmaxf(mx, __shfl_xor(mx, off));
    }
    __shared__ float smn[4], smx[4];
    const int wave = threadIdx.x >> 6;
    if ((threadIdx.x & 63) == 0) { smn[wave] = mn; smx[wave] = mx; }
    __syncthreads();
    if (threadIdx.x == 0) {
        float bmn = fminf(fminf(smn[0], smn[1]), fminf(smn[2], smn[3]));
        float bmx = fmaxf(fmaxf(smx[0], smx[1]), fmaxf(smx[2], smx[3]));
        atomicMin(&mm[2*bc],   __float_as_uint(bmn));  // float-bit order ok: all >= 0
        atomicMax(&mm[2*bc+1], __float_as_uint(bmx));
    }
}

// Normalize pred channel in place: (v - mn) / ((mx - mn) + eps) * SCALE
__global__ __launch_bounds__(256) void norm_kernel(float* __restrict__ out,
                                                   const unsigned int* __restrict__ mm) {
    const int tid = blockIdx.x * 256 + threadIdx.x;   // float4 index over pred elems
    const int per_bc4 = K_ * HW_ / 4;                 // 65536
    const int bc = tid / per_bc4;
    if (bc >= NBC) return;
    const size_t n4 = (size_t)(tid - bc * per_bc4) + (size_t)(bc * 2) * per_bc4;
    const float mnv = __uint_as_float(mm[2*bc]);
    const float mxv = __uint_as_float(mm[2*bc+1]);
    const float den = (mxv - mnv) + EPS_;
    float4 v = ((float4*)out)[n4];
    v.x = (v.x - mnv) / den * SCALE_;
    v.y = (v.y - mnv) / den * SCALE_;
    v.z = (v.z - mnv) / den * SCALE_;
    v.w = (v.w - mnv) / den * SCALE_;
    ((float4*)out)[n4] = v;
}

extern "C" void kernel_launch(void* const* d_in, const int* in_sizes, int n_in,
                              void* d_out, int out_size, void* d_ws, size_t ws_size,
                              hipStream_t stream) {
    const float* x = (const float*)d_in[0];
    float* out = (float*)d_out;
    unsigned int* mm = (unsigned int*)d_ws;

    hipLaunchKernelGGL(init_mm_kernel, dim3(1), dim3(64), 0, stream, mm);

    const int threads1 = NBC * HW_;                   // 262144 columns
    hipLaunchKernelGGL(topk_kernel, dim3(threads1 / 256), dim3(256), 0, stream,
                       x, out, mm);

    const int threads2 = NBC * K_ * HW_ / 4;          // 262144
    hipLaunchKernelGGL(norm_kernel, dim3(threads2 / 256), dim3(256), 0, stream,
                       out, mm);
}